// Round 6
// baseline (3609.792 us; speedup 1.0000x reference)
//
#include <hip/hip_runtime.h>
#include <cstdint>
#include <cstddef>
#include <cmath>

#define H  2048
#define BB 2048   // batch
#define TT 64     // time steps
#define NC 10     // classes
#define BK 64     // K-chunk per staging iter (8 x 16B chunks per row)

typedef __bf16 bf16;
typedef bf16  bf16x8 __attribute__((ext_vector_type(8)));
typedef bf16  bf16x4 __attribute__((ext_vector_type(4)));
typedef float f32x4  __attribute__((ext_vector_type(4)));

// ---------------------------------------------------------------------------
// async global->LDS, 16B per lane. LDS dest is wave-uniform base + lane*16.
// ---------------------------------------------------------------------------
__device__ __forceinline__ void load_lds16(const void* g, void* l) {
    __builtin_amdgcn_global_load_lds(
        (__attribute__((address_space(1))) void*)(void*)g,
        (__attribute__((address_space(3))) void*)l,
        16, 0, 0);
}

// ---------------------------------------------------------------------------
// fp32 -> bf16 convert (W_hh), 4 elems/thread
// ---------------------------------------------------------------------------
__global__ void f32_to_bf16_kernel(const float* __restrict__ in,
                                   bf16* __restrict__ out, int n) {
    int i = (blockIdx.x * blockDim.x + threadIdx.x) * 4;
    if (i + 3 < n) {
        float4 v = *(const float4*)(in + i);
        bf16x4 o;
        o[0] = (bf16)v.x; o[1] = (bf16)v.y; o[2] = (bf16)v.z; o[3] = (bf16)v.w;
        *(bf16x4*)(out + i) = o;
    }
}

// ---------------------------------------------------------------------------
// t = 0: S[b,i] = tanh(Whx[i]*x[b,0] + bh[i]).  One block per batch row.
// ---------------------------------------------------------------------------
__global__ void rnn_init(const float* __restrict__ x,     // [B, T]
                         const float* __restrict__ Whx,   // [H]
                         const float* __restrict__ bh,    // [H]
                         bf16* __restrict__ S) {          // [B, H]
    int b  = blockIdx.x;
    int i0 = threadIdx.x * 8;
    float xv = x[(size_t)b * TT];
    bf16x8 o;
#pragma unroll
    for (int j = 0; j < 8; ++j)
        o[j] = (bf16)tanhf(Whx[i0 + j] * xv + bh[i0 + j]);
    *(bf16x8*)(S + (size_t)b * H + i0) = o;
}

// ---------------------------------------------------------------------------
// One RNN time step:
//   Sw[b,i] = tanh( sum_k Sr[b,k]*Wb[i,k] + Whx[i]*x[b,t] + bh[i] )
//
// 128x128 tile, grid 256, 64x64 per wave, BK=64.
// A (state S) is double-buffered through XOR-swizzled LDS (32 KB total,
// conflict-free per Round-5 measurement). B (W_hh) SKIPS LDS: the MFMA
// B-fragment B[n=lane&15][k=quad*8+j] is loaded directly from global as a
// b128 at Wb + row*H + k-chunk (16 rows x 64 B segments per wave-instr),
// hitting the XCD-local L2-resident W slice (1 MB/XCD) and L1 (each line
// shared by the 2 qn-waves). This moves ~half the LDS-pipe traffic onto
// the otherwise-idle L1/L2 path. B regs are prefetched one k-chunk ahead
// (ping-pong via unroll-2); the vmcnt(0) drain at __syncthreads makes them
// ready exactly when consumed.
// ---------------------------------------------------------------------------
__launch_bounds__(256)
__global__ void rnn_step(const float* __restrict__ x,     // [B, T]
                         const float* __restrict__ Whx,   // [H]
                         const float* __restrict__ bh,    // [H]
                         const bf16*  __restrict__ Wb,    // [H, H] bf16
                         const bf16*  __restrict__ Sr,    // [B, H] read
                         bf16* __restrict__ Sw,           // [B, H] write
                         int t) {
    __shared__ __align__(16) bf16 As[2][128 * BK];  // 2 x 16 KB (S tile)

    const int tid  = threadIdx.x;
    const int w    = tid >> 6;          // wave 0..3
    const int lane = tid & 63;

    // XCD-aware mapping: 2 bn-tiles per XCD -> 1 MB W-slice L2-resident.
    const int xcd = blockIdx.x & 7;
    const int loc = blockIdx.x >> 3;              // 0..31
    const int bn0 = (xcd * 2 + (loc & 1)) * 128;  // hidden-col tile origin
    const int bm0 = (loc >> 1) * 128;             // batch-row tile origin

    const int qm   = (w & 1) * 64;                // wave quadrant: 64x64
    const int qn   = (w >> 1) * 64;
    const int lrow = lane & 15;
    const int quad = lane >> 4;

    const int s_r = tid >> 3;                     // staging row in 32-group
    const int s_l = tid & 7;                      // staging LDS chunk in row

    // per-lane W row base pointers for the 4 fn fragments (constant over k)
    const bf16* wrow[4];
#pragma unroll
    for (int f = 0; f < 4; ++f)
        wrow[f] = Wb + (size_t)(bn0 + qn + f * 16 + lrow) * H + quad * 8;

    // stage A K-chunk k0 into LDS buffer b (4 wave-instrs / wave)
    auto stageA = [&](int b, int k0) {
#pragma unroll
        for (int i = 0; i < 4; ++i) {
            int r = i * 32 + s_r;                 // tile row 0..127
            int g = s_l ^ (r & 7);                // swizzled source chunk
            load_lds16(Sr + (size_t)(bm0 + r) * H + k0 + g * 8,
                       &As[b][(i * 256 + w * 64) * 8]);
        }
    };
    // load B frags for K-chunk k0 into registers (8 b128 loads / lane)
    auto loadB = [&](bf16x8 (&B)[2][4], int k0) {
#pragma unroll
        for (int kc = 0; kc < 2; ++kc)
#pragma unroll
            for (int f = 0; f < 4; ++f)
                B[kc][f] = *(const bf16x8*)(wrow[f] + k0 + kc * 32);
    };

    f32x4 acc[4][4];
#pragma unroll
    for (int i = 0; i < 4; ++i)
#pragma unroll
        for (int j = 0; j < 4; ++j) acc[i][j] = (f32x4){0.f, 0.f, 0.f, 0.f};

    bf16x8 B0[2][4], B1[2][4];

    auto compute = [&](const bf16* Ab, bf16x8 (&B)[2][4]) {
#pragma unroll
        for (int kc = 0; kc < 2; ++kc) {
            bf16x8 af[4];
#pragma unroll
            for (int f = 0; f < 4; ++f) {
                int row = qm + f * 16 + lrow;
                int g   = kc * 4 + quad;
                int l   = g ^ (row & 7);
                af[f] = *(const bf16x8*)&Ab[(row * 8 + l) * 8];
            }
#pragma unroll
            for (int fm = 0; fm < 4; ++fm)
#pragma unroll
                for (int fn = 0; fn < 4; ++fn)
                    acc[fm][fn] = __builtin_amdgcn_mfma_f32_16x16x32_bf16(
                        af[fm], B[kc][fn], acc[fm][fn], 0, 0, 0);
        }
    };

    stageA(0, 0);
    loadB(B0, 0);

    for (int k0 = 0; k0 < H; k0 += 2 * BK) {
        // chunk 0: LDS buf 0, regs B0
        __syncthreads();                       // drains stageA(k0) + B0
        if (k0 + BK < H) { stageA(1, k0 + BK); loadB(B1, k0 + BK); }
        compute(As[0], B0);
        // chunk 1: LDS buf 1, regs B1
        __syncthreads();                       // drains stageA(k0+BK) + B1
        if (k0 + 2 * BK < H) { stageA(0, k0 + 2 * BK); loadB(B0, k0 + 2 * BK); }
        compute(As[1], B1);
    }

    // epilogue: z += Whx[i]*x[b,t] + bh[i]; tanh; store bf16.
    // C layout (16x16x32): col = lane&15, row = quad*4 + reg  [m89-verified]
#pragma unroll
    for (int fm = 0; fm < 4; ++fm) {
        int rb = bm0 + qm + fm * 16 + quad * 4;
        float xv[4];
#pragma unroll
        for (int r = 0; r < 4; ++r) xv[r] = x[(size_t)(rb + r) * TT + t];
#pragma unroll
        for (int fn = 0; fn < 4; ++fn) {
            int col = bn0 + qn + fn * 16 + lrow;
            float wx = Whx[col], bb = bh[col];
#pragma unroll
            for (int r = 0; r < 4; ++r) {
                float z = acc[fm][fn][r] + wx * xv[r] + bb;
                Sw[(size_t)(rb + r) * H + col] = (bf16)tanhf(z);
            }
        }
    }
}

// ---------------------------------------------------------------------------
// out[b,c] = sum_h Why[h,c] * S[b,h] + bp[c]   (S = h_T^T, [B,H] bf16)
// one block per batch row
// ---------------------------------------------------------------------------
__global__ void out_proj(const bf16* __restrict__ S,
                         const float* __restrict__ Why,   // [H, C]
                         const float* __restrict__ bp,    // [C]
                         float* __restrict__ out) {       // [B, C]
    int b = blockIdx.x, tid = threadIdx.x;
    float p[NC];
#pragma unroll
    for (int c = 0; c < NC; ++c) p[c] = 0.f;
    for (int h = tid; h < H; h += 256) {
        float s = (float)S[(size_t)b * H + h];
        const float* wr = Why + h * NC;
#pragma unroll
        for (int c = 0; c < NC; ++c) p[c] += s * wr[c];
    }
    __shared__ float red[256 * NC];
#pragma unroll
    for (int c = 0; c < NC; ++c) red[tid * NC + c] = p[c];
    __syncthreads();
    for (int s = 128; s > 0; s >>= 1) {
        if (tid < s)
#pragma unroll
            for (int c = 0; c < NC; ++c) red[tid * NC + c] += red[(tid + s) * NC + c];
        __syncthreads();
    }
    if (tid < NC) out[(size_t)b * NC + tid] = red[tid] + bp[tid];
}

// ---------------------------------------------------------------------------
extern "C" void kernel_launch(void* const* d_in, const int* in_sizes, int n_in,
                              void* d_out, int out_size, void* d_ws, size_t ws_size,
                              hipStream_t stream) {
    const float* x   = (const float*)d_in[0];   // [B, T]
    const float* Whx = (const float*)d_in[1];   // [H, 1]
    const float* Whh = (const float*)d_in[2];   // [H, H]
    const float* Why = (const float*)d_in[3];   // [H, C]
    const float* bh  = (const float*)d_in[4];   // [H, 1]
    const float* bp  = (const float*)d_in[5];   // [C, 1]
    float* out = (float*)d_out;

    // workspace: Wb (8 MB) | S0 (8 MB) | S1 (8 MB)
    bf16* Wb = (bf16*)d_ws;
    bf16* S0 = (bf16*)((char*)d_ws + (size_t)8 * 1024 * 1024);
    bf16* S1 = (bf16*)((char*)d_ws + (size_t)16 * 1024 * 1024);

    hipLaunchKernelGGL(f32_to_bf16_kernel, dim3((H * H) / (256 * 4)), dim3(256),
                       0, stream, Whh, Wb, H * H);

    // t = 0 writes S1; step t reads (t&1 ? S1 : S0), writes the other.
    hipLaunchKernelGGL(rnn_init, dim3(BB), dim3(256), 0, stream, x, Whx, bh, S1);

    for (int t = 1; t < TT; ++t) {
        const bf16* Srd = (t & 1) ? S1 : S0;
        bf16*       Swr = (t & 1) ? S0 : S1;
        hipLaunchKernelGGL(rnn_step, dim3(256), dim3(256), 0, stream,
                           x, Whx, bh, Wb, Srd, Swr, t);
    }

    // t=63 (odd) wrote S0
    hipLaunchKernelGGL(out_proj, dim3(BB), dim3(256), 0, stream, S0, Why, bp, out);
}

// Round 7
// 2138.337 us; speedup vs baseline: 1.6881x; 1.6881x over previous
//
#include <hip/hip_runtime.h>
#include <cstdint>
#include <cstddef>
#include <cmath>

#define H  2048
#define BB 2048   // batch
#define TT 64     // time steps
#define NC 10     // classes
#define BK 64     // K-chunk per staging iter (8 x 16B chunks per row)

typedef __bf16 bf16;
typedef bf16  bf16x8 __attribute__((ext_vector_type(8)));
typedef bf16  bf16x4 __attribute__((ext_vector_type(4)));
typedef float f32x4  __attribute__((ext_vector_type(4)));

// ---------------------------------------------------------------------------
// async global->LDS, 16B per lane. LDS dest is wave-uniform base + lane*16.
// ---------------------------------------------------------------------------
__device__ __forceinline__ void load_lds16(const void* g, void* l) {
    __builtin_amdgcn_global_load_lds(
        (__attribute__((address_space(1))) void*)(void*)g,
        (__attribute__((address_space(3))) void*)l,
        16, 0, 0);
}

// ---------------------------------------------------------------------------
// fp32 -> bf16 convert (W_hh), 4 elems/thread
// ---------------------------------------------------------------------------
__global__ void f32_to_bf16_kernel(const float* __restrict__ in,
                                   bf16* __restrict__ out, int n) {
    int i = (blockIdx.x * blockDim.x + threadIdx.x) * 4;
    if (i + 3 < n) {
        float4 v = *(const float4*)(in + i);
        bf16x4 o;
        o[0] = (bf16)v.x; o[1] = (bf16)v.y; o[2] = (bf16)v.z; o[3] = (bf16)v.w;
        *(bf16x4*)(out + i) = o;
    }
}

// ---------------------------------------------------------------------------
// t = 0: S[b,i] = tanh(Whx[i]*x[b,0] + bh[i]).  One block per batch row.
// ---------------------------------------------------------------------------
__global__ void rnn_init(const float* __restrict__ x,     // [B, T]
                         const float* __restrict__ Whx,   // [H]
                         const float* __restrict__ bh,    // [H]
                         bf16* __restrict__ S) {          // [B, H]
    int b  = blockIdx.x;
    int i0 = threadIdx.x * 8;
    float xv = x[(size_t)b * TT];
    bf16x8 o;
#pragma unroll
    for (int j = 0; j < 8; ++j)
        o[j] = (bf16)tanhf(Whx[i0 + j] * xv + bh[i0 + j]);
    *(bf16x8*)(S + (size_t)b * H + i0) = o;
}

// ---------------------------------------------------------------------------
// One RNN time step:
//   Sw[b,i] = tanh( sum_k Sr[b,k]*Wb[i,k] + Whx[i]*x[b,t] + bh[i] )
//
// Round-7 = Round-4 (best: 30 us/step) + double-buffered LDS, nothing else.
// 128(m) x 64(n) tile, grid 512 -> 2 blocks/CU (m114 co-residency, the
// proven dominant overlap mechanism) AND intra-block pipelining: the
// stage issued after each barrier has a full compute phase in flight before
// the next barrier drains it. LDS = 2 x (16+8) = 48 KB -> 96 KB/CU for the
// two blocks, fits the 160 KB pool.
//
// LDS XOR swizzle (proven conflict-free in R5/R6: SQ_LDS_BANK_CONFLICT=0):
// 16B chunk l of tile row r holds global chunk l^(r&7); swizzle applied on
// the global SOURCE address since global_load_lds forces dest=base+lane*16.
// ---------------------------------------------------------------------------
__launch_bounds__(256, 2)
__global__ void rnn_step(const float* __restrict__ x,     // [B, T]
                         const float* __restrict__ Whx,   // [H]
                         const float* __restrict__ bh,    // [H]
                         const bf16*  __restrict__ Wb,    // [H, H] bf16
                         const bf16*  __restrict__ Sr,    // [B, H] read
                         bf16* __restrict__ Sw,           // [B, H] write
                         int t) {
    __shared__ __align__(16) bf16 As[2][128 * BK];  // 2 x 16 KB (S tile)
    __shared__ __align__(16) bf16 Bs[2][64 * BK];   // 2 x  8 KB (W tile)

    const int tid  = threadIdx.x;
    const int w    = tid >> 6;          // wave 0..3
    const int lane = tid & 63;

    // XCD-aware mapping (as R4): 4 bn-tiles/XCD -> 1 MB W-slice L2-resident.
    const int xcd = blockIdx.x & 7;
    const int loc = blockIdx.x >> 3;             // 0..63
    const int bn0 = (xcd * 4 + (loc & 3)) * 64;  // hidden-col tile origin
    const int bm0 = (loc >> 2) * 128;            // batch-row tile origin

    const int qm   = (w & 1) * 64;               // wave m-quadrant (64 rows)
    const int qn   = (w >> 1) * 32;              // wave n-quadrant (32 cols)
    const int lrow = lane & 15;
    const int quad = lane >> 4;

    const int s_r = tid >> 3;                    // staging row within 32-group
    const int s_l = tid & 7;                     // staging LDS chunk in row

    // stage K-chunk k0 of both tiles into buffer b (6 wave-instrs / wave)
    auto stage = [&](int b, int k0) {
#pragma unroll
        for (int i = 0; i < 4; ++i) {
            int r = i * 32 + s_r;                 // tile row 0..127
            int g = s_l ^ (r & 7);                // swizzled source chunk
            load_lds16(Sr + (size_t)(bm0 + r) * H + k0 + g * 8,
                       &As[b][(i * 256 + w * 64) * 8]);
        }
#pragma unroll
        for (int i = 0; i < 2; ++i) {
            int r = i * 32 + s_r;                 // tile row 0..63
            int g = s_l ^ (r & 7);
            load_lds16(Wb + (size_t)(bn0 + r) * H + k0 + g * 8,
                       &Bs[b][(i * 256 + w * 64) * 8]);
        }
    };

    f32x4 acc[4][2];
#pragma unroll
    for (int i = 0; i < 4; ++i)
#pragma unroll
        for (int j = 0; j < 2; ++j) acc[i][j] = (f32x4){0.f, 0.f, 0.f, 0.f};

    stage(0, 0);

    for (int k0 = 0; k0 < H; k0 += BK) {
        const int b = (k0 >> 6) & 1;
        __syncthreads();                 // drains prefetch into buf b; also
                                         // fences last iter's reads of b^1
        if (k0 + BK < H) stage(b ^ 1, k0 + BK);   // in flight through compute

#pragma unroll
        for (int kc = 0; kc < 2; ++kc) {
            bf16x8 af[4], bfr[2];
#pragma unroll
            for (int f = 0; f < 4; ++f) {
                int row = qm + f * 16 + lrow;
                int g   = kc * 4 + quad;
                int l   = g ^ (row & 7);
                af[f] = *(const bf16x8*)&As[b][(row * 8 + l) * 8];
            }
#pragma unroll
            for (int f = 0; f < 2; ++f) {
                int row = qn + f * 16 + lrow;
                int g   = kc * 4 + quad;
                int l   = g ^ (row & 7);
                bfr[f] = *(const bf16x8*)&Bs[b][(row * 8 + l) * 8];
            }
#pragma unroll
            for (int fm = 0; fm < 4; ++fm)
#pragma unroll
                for (int fn = 0; fn < 2; ++fn)
                    acc[fm][fn] = __builtin_amdgcn_mfma_f32_16x16x32_bf16(
                        af[fm], bfr[fn], acc[fm][fn], 0, 0, 0);
        }
    }

    // epilogue: z += Whx[i]*x[b,t] + bh[i]; tanh; store bf16.
    // C layout (16x16x32): col = lane&15, row = quad*4 + reg  [m89-verified]
#pragma unroll
    for (int fm = 0; fm < 4; ++fm) {
        int rb = bm0 + qm + fm * 16 + quad * 4;
        float xv[4];
#pragma unroll
        for (int r = 0; r < 4; ++r) xv[r] = x[(size_t)(rb + r) * TT + t];
#pragma unroll
        for (int fn = 0; fn < 2; ++fn) {
            int col = bn0 + qn + fn * 16 + lrow;
            float wx = Whx[col], bb = bh[col];
#pragma unroll
            for (int r = 0; r < 4; ++r) {
                float z = acc[fm][fn][r] + wx * xv[r] + bb;
                Sw[(size_t)(rb + r) * H + col] = (bf16)tanhf(z);
            }
        }
    }
}

// ---------------------------------------------------------------------------
// out[b,c] = sum_h Why[h,c] * S[b,h] + bp[c]   (S = h_T^T, [B,H] bf16)
// one block per batch row
// ---------------------------------------------------------------------------
__global__ void out_proj(const bf16* __restrict__ S,
                         const float* __restrict__ Why,   // [H, C]
                         const float* __restrict__ bp,    // [C]
                         float* __restrict__ out) {       // [B, C]
    int b = blockIdx.x, tid = threadIdx.x;
    float p[NC];
#pragma unroll
    for (int c = 0; c < NC; ++c) p[c] = 0.f;
    for (int h = tid; h < H; h += 256) {
        float s = (float)S[(size_t)b * H + h];
        const float* wr = Why + h * NC;
#pragma unroll
        for (int c = 0; c < NC; ++c) p[c] += s * wr[c];
    }
    __shared__ float red[256 * NC];
#pragma unroll
    for (int c = 0; c < NC; ++c) red[tid * NC + c] = p[c];
    __syncthreads();
    for (int s = 128; s > 0; s >>= 1) {
        if (tid < s)
#pragma unroll
            for (int c = 0; c < NC; ++c) red[tid * NC + c] += red[(tid + s) * NC + c];
        __syncthreads();
    }
    if (tid < NC) out[(size_t)b * NC + tid] = red[tid] + bp[tid];
}

// ---------------------------------------------------------------------------
extern "C" void kernel_launch(void* const* d_in, const int* in_sizes, int n_in,
                              void* d_out, int out_size, void* d_ws, size_t ws_size,
                              hipStream_t stream) {
    const float* x   = (const float*)d_in[0];   // [B, T]
    const float* Whx = (const float*)d_in[1];   // [H, 1]
    const float* Whh = (const float*)d_in[2];   // [H, H]
    const float* Why = (const float*)d_in[3];   // [H, C]
    const float* bh  = (const float*)d_in[4];   // [H, 1]
    const float* bp  = (const float*)d_in[5];   // [C, 1]
    float* out = (float*)d_out;

    // workspace: Wb (8 MB) | S0 (8 MB) | S1 (8 MB)
    bf16* Wb = (bf16*)d_ws;
    bf16* S0 = (bf16*)((char*)d_ws + (size_t)8 * 1024 * 1024);
    bf16* S1 = (bf16*)((char*)d_ws + (size_t)16 * 1024 * 1024);

    hipLaunchKernelGGL(f32_to_bf16_kernel, dim3((H * H) / (256 * 4)), dim3(256),
                       0, stream, Whh, Wb, H * H);

    // t = 0 writes S1; step t reads (t&1 ? S1 : S0), writes the other.
    hipLaunchKernelGGL(rnn_init, dim3(BB), dim3(256), 0, stream, x, Whx, bh, S1);

    for (int t = 1; t < TT; ++t) {
        const bf16* Srd = (t & 1) ? S1 : S0;
        bf16*       Swr = (t & 1) ? S0 : S1;
        hipLaunchKernelGGL(rnn_step, dim3(512), dim3(256), 0, stream,
                           x, Whx, bh, Wb, Srd, Swr, t);
    }

    // t=63 (odd) wrote S0
    hipLaunchKernelGGL(out_proj, dim3(BB), dim3(256), 0, stream, S0, Why, bp, out);
}

// Round 8
// 1997.176 us; speedup vs baseline: 1.8074x; 1.0707x over previous
//
#include <hip/hip_runtime.h>
#include <cstdint>
#include <cstddef>
#include <cmath>

#define H  2048
#define BB 2048   // batch
#define TT 64     // time steps
#define NC 10     // classes
#define BK 64     // K-chunk per staging iter (8 x 16B chunks per row)

typedef __bf16 bf16;
typedef bf16  bf16x8 __attribute__((ext_vector_type(8)));
typedef bf16  bf16x4 __attribute__((ext_vector_type(4)));
typedef float f32x4  __attribute__((ext_vector_type(4)));

// ---------------------------------------------------------------------------
// async global->LDS, 16B per lane. LDS dest is wave-uniform base + lane*16.
// ---------------------------------------------------------------------------
__device__ __forceinline__ void load_lds16(const void* g, void* l) {
    __builtin_amdgcn_global_load_lds(
        (__attribute__((address_space(1))) void*)(void*)g,
        (__attribute__((address_space(3))) void*)l,
        16, 0, 0);
}

// ---------------------------------------------------------------------------
// fp32 -> bf16 convert (W_hh), 4 elems/thread
// ---------------------------------------------------------------------------
__global__ void f32_to_bf16_kernel(const float* __restrict__ in,
                                   bf16* __restrict__ out, int n) {
    int i = (blockIdx.x * blockDim.x + threadIdx.x) * 4;
    if (i + 3 < n) {
        float4 v = *(const float4*)(in + i);
        bf16x4 o;
        o[0] = (bf16)v.x; o[1] = (bf16)v.y; o[2] = (bf16)v.z; o[3] = (bf16)v.w;
        *(bf16x4*)(out + i) = o;
    }
}

// ---------------------------------------------------------------------------
// t = 0: S[b,i] = tanh(Whx[i]*x[b,0] + bh[i]).  One block per batch row.
// ---------------------------------------------------------------------------
__global__ void rnn_init(const float* __restrict__ x,     // [B, T]
                         const float* __restrict__ Whx,   // [H]
                         const float* __restrict__ bh,    // [H]
                         bf16* __restrict__ S) {          // [B, H]
    int b  = blockIdx.x;
    int i0 = threadIdx.x * 8;
    float xv = x[(size_t)b * TT];
    bf16x8 o;
#pragma unroll
    for (int j = 0; j < 8; ++j)
        o[j] = (bf16)tanhf(Whx[i0 + j] * xv + bh[i0 + j]);
    *(bf16x8*)(S + (size_t)b * H + i0) = o;
}

// ---------------------------------------------------------------------------
// One RNN time step:
//   Sw[b,i] = tanh( sum_k Sr[b,k]*Wb[i,k] + Whx[i]*x[b,t] + bh[i] )
//
// Round-8 = Round-4 (best: ~30 us/step) with ONE change: XCD ownership is
// swapped from bn (W columns) to bm (batch rows).
//   bm0 = (xcd*2 + loc&1)*128  -> each XCD owns a 256-row S-slice (1 MB).
// S-reads hit the local L2, and S-WRITES land in the same XCD's L2 that
// re-reads them next step: the inter-step producer-consumer loop never
// leaves the XCD (R4's bn-mapping left S thrashing 8 MB/XCD through L3/HBM
// -> FETCH_SIZE 38 MB/step). W becomes the redundant operand, served from
// the L3-hot, step-invariant 8 MB copy.
//
// 128(m) x 64(n) tile, grid 512 -> 2 blocks/CU (m114 co-residency — the
// proven overlap mechanism; R5/R6/R7 showed intra-block dbuf adds nothing).
// Single-buffered 24 KB LDS, XOR-swizzled (SQ_LDS_BANK_CONFLICT = 0).
// ---------------------------------------------------------------------------
__launch_bounds__(256)
__global__ void rnn_step(const float* __restrict__ x,     // [B, T]
                         const float* __restrict__ Whx,   // [H]
                         const float* __restrict__ bh,    // [H]
                         const bf16*  __restrict__ Wb,    // [H, H] bf16
                         const bf16*  __restrict__ Sr,    // [B, H] read
                         bf16* __restrict__ Sw,           // [B, H] write
                         int t) {
    __shared__ __align__(16) bf16 As[128 * BK];  // 16 KB (S tile, m-rows)
    __shared__ __align__(16) bf16 Bs[64 * BK];   //  8 KB (W tile, n-rows)

    const int tid  = threadIdx.x;
    const int w    = tid >> 6;          // wave 0..3
    const int lane = tid & 63;

    // XCD-aware mapping: XCD owns batch rows (S producer-consumer locality).
    const int xcd = blockIdx.x & 7;
    const int loc = blockIdx.x >> 3;              // 0..63
    const int bm0 = (xcd * 2 + (loc & 1)) * 128;  // batch-row tile origin
    const int bn0 = (loc >> 1) * 64;              // hidden-col tile origin

    const int qm   = (w & 1) * 64;               // wave m-quadrant (64 rows)
    const int qn   = (w >> 1) * 32;              // wave n-quadrant (32 cols)
    const int lrow = lane & 15;
    const int quad = lane >> 4;

    const int s_r = tid >> 3;                    // staging row within 32-group
    const int s_l = tid & 7;                     // staging LDS chunk in row

    f32x4 acc[4][2];
#pragma unroll
    for (int i = 0; i < 4; ++i)
#pragma unroll
        for (int j = 0; j < 2; ++j) acc[i][j] = (f32x4){0.f, 0.f, 0.f, 0.f};

    for (int k0 = 0; k0 < H; k0 += BK) {
        if (k0) __syncthreads();   // previous iter's LDS reads done
        // A tile: 128 rows x 8 chunks; 4 wave-instrs
#pragma unroll
        for (int i = 0; i < 4; ++i) {
            int r = i * 32 + s_r;                 // tile row 0..127
            int g = s_l ^ (r & 7);                // swizzled source chunk
            load_lds16(Sr + (size_t)(bm0 + r) * H + k0 + g * 8,
                       &As[(i * 256 + w * 64) * 8]);
        }
        // B tile: 64 rows x 8 chunks; 2 wave-instrs
#pragma unroll
        for (int i = 0; i < 2; ++i) {
            int r = i * 32 + s_r;                 // tile row 0..63
            int g = s_l ^ (r & 7);
            load_lds16(Wb + (size_t)(bn0 + r) * H + k0 + g * 8,
                       &Bs[(i * 256 + w * 64) * 8]);
        }
        __syncthreads();   // staging complete (barrier drains vmcnt)

#pragma unroll
        for (int kc = 0; kc < 2; ++kc) {
            bf16x8 af[4], bfr[2];
#pragma unroll
            for (int f = 0; f < 4; ++f) {
                int row = qm + f * 16 + lrow;
                int g   = kc * 4 + quad;
                int l   = g ^ (row & 7);
                af[f] = *(const bf16x8*)&As[(row * 8 + l) * 8];
            }
#pragma unroll
            for (int f = 0; f < 2; ++f) {
                int row = qn + f * 16 + lrow;
                int g   = kc * 4 + quad;
                int l   = g ^ (row & 7);
                bfr[f] = *(const bf16x8*)&Bs[(row * 8 + l) * 8];
            }
#pragma unroll
            for (int fm = 0; fm < 4; ++fm)
#pragma unroll
                for (int fn = 0; fn < 2; ++fn)
                    acc[fm][fn] = __builtin_amdgcn_mfma_f32_16x16x32_bf16(
                        af[fm], bfr[fn], acc[fm][fn], 0, 0, 0);
        }
    }

    // epilogue: z += Whx[i]*x[b,t] + bh[i]; tanh; store bf16.
    // C layout (16x16x32): col = lane&15, row = quad*4 + reg  [m89-verified]
#pragma unroll
    for (int fm = 0; fm < 4; ++fm) {
        int rb = bm0 + qm + fm * 16 + quad * 4;
        float xv[4];
#pragma unroll
        for (int r = 0; r < 4; ++r) xv[r] = x[(size_t)(rb + r) * TT + t];
#pragma unroll
        for (int fn = 0; fn < 2; ++fn) {
            int col = bn0 + qn + fn * 16 + lrow;
            float wx = Whx[col], bb = bh[col];
#pragma unroll
            for (int r = 0; r < 4; ++r) {
                float z = acc[fm][fn][r] + wx * xv[r] + bb;
                Sw[(size_t)(rb + r) * H + col] = (bf16)tanhf(z);
            }
        }
    }
}

// ---------------------------------------------------------------------------
// out[b,c] = sum_h Why[h,c] * S[b,h] + bp[c]   (S = h_T^T, [B,H] bf16)
// one block per batch row
// ---------------------------------------------------------------------------
__global__ void out_proj(const bf16* __restrict__ S,
                         const float* __restrict__ Why,   // [H, C]
                         const float* __restrict__ bp,    // [C]
                         float* __restrict__ out) {       // [B, C]
    int b = blockIdx.x, tid = threadIdx.x;
    float p[NC];
#pragma unroll
    for (int c = 0; c < NC; ++c) p[c] = 0.f;
    for (int h = tid; h < H; h += 256) {
        float s = (float)S[(size_t)b * H + h];
        const float* wr = Why + h * NC;
#pragma unroll
        for (int c = 0; c < NC; ++c) p[c] += s * wr[c];
    }
    __shared__ float red[256 * NC];
#pragma unroll
    for (int c = 0; c < NC; ++c) red[tid * NC + c] = p[c];
    __syncthreads();
    for (int s = 128; s > 0; s >>= 1) {
        if (tid < s)
#pragma unroll
            for (int c = 0; c < NC; ++c) red[tid * NC + c] += red[(tid + s) * NC + c];
        __syncthreads();
    }
    if (tid < NC) out[(size_t)b * NC + tid] = red[tid] + bp[tid];
}

// ---------------------------------------------------------------------------
extern "C" void kernel_launch(void* const* d_in, const int* in_sizes, int n_in,
                              void* d_out, int out_size, void* d_ws, size_t ws_size,
                              hipStream_t stream) {
    const float* x   = (const float*)d_in[0];   // [B, T]
    const float* Whx = (const float*)d_in[1];   // [H, 1]
    const float* Whh = (const float*)d_in[2];   // [H, H]
    const float* Why = (const float*)d_in[3];   // [H, C]
    const float* bh  = (const float*)d_in[4];   // [H, 1]
    const float* bp  = (const float*)d_in[5];   // [C, 1]
    float* out = (float*)d_out;

    // workspace: Wb (8 MB) | S0 (8 MB) | S1 (8 MB)
    bf16* Wb = (bf16*)d_ws;
    bf16* S0 = (bf16*)((char*)d_ws + (size_t)8 * 1024 * 1024);
    bf16* S1 = (bf16*)((char*)d_ws + (size_t)16 * 1024 * 1024);

    hipLaunchKernelGGL(f32_to_bf16_kernel, dim3((H * H) / (256 * 4)), dim3(256),
                       0, stream, Whh, Wb, H * H);

    // t = 0 writes S1; step t reads (t&1 ? S1 : S0), writes the other.
    hipLaunchKernelGGL(rnn_init, dim3(BB), dim3(256), 0, stream, x, Whx, bh, S1);

    for (int t = 1; t < TT; ++t) {
        const bf16* Srd = (t & 1) ? S1 : S0;
        bf16*       Swr = (t & 1) ? S0 : S1;
        hipLaunchKernelGGL(rnn_step, dim3(512), dim3(256), 0, stream,
                           x, Whx, bh, Wb, Srd, Swr, t);
    }

    // t=63 (odd) wrote S0
    hipLaunchKernelGGL(out_proj, dim3(BB), dim3(256), 0, stream, S0, Why, bp, out);
}

// Round 9
// 1890.768 us; speedup vs baseline: 1.9092x; 1.0563x over previous
//
#include <hip/hip_runtime.h>
#include <cstdint>
#include <cstddef>
#include <cmath>

#define H  2048
#define BB 2048   // batch
#define TT 64     // time steps
#define NC 10     // classes
#define BK 64     // K-chunk per staging iter (8 x 16B chunks per row)

typedef __bf16 bf16;
typedef bf16  bf16x8 __attribute__((ext_vector_type(8)));
typedef bf16  bf16x4 __attribute__((ext_vector_type(4)));
typedef float f32x4  __attribute__((ext_vector_type(4)));

// ---------------------------------------------------------------------------
// async global->LDS, 16B per lane. LDS dest is wave-uniform base + lane*16.
// ---------------------------------------------------------------------------
__device__ __forceinline__ void load_lds16(const void* g, void* l) {
    __builtin_amdgcn_global_load_lds(
        (__attribute__((address_space(1))) void*)(void*)g,
        (__attribute__((address_space(3))) void*)l,
        16, 0, 0);
}

// ---------------------------------------------------------------------------
// W_hh fp32 -> bf16, shuffled into MFMA-B-frag-major layout:
// subtile (n16, k32) = 16 n-rows x 32 k, 1024 B, at id = n16*64 + k32.
// Within a subtile, dest lane-slot l (16 B) holds
//   W[n16*16 + (l&15)][k32*32 + (l>>4)*8 .. +8]
// i.e. exactly the v_mfma_f32_16x16x32_bf16 B-operand fragment, so a wave's
// B-frag load is ONE coalesced 1 KB segment: Wshuf + id*512 + lane*8 (bf16).
// One thread produces one 16 B dst chunk.
// ---------------------------------------------------------------------------
__global__ void w_shuffle_kernel(const float* __restrict__ Whh,
                                 bf16* __restrict__ Wshuf) {
    int tid = blockIdx.x * blockDim.x + threadIdx.x;   // 0 .. H*H/8-1
    int sub = tid >> 6;          // subtile id
    int l   = tid & 63;          // dest lane slot
    int n16 = sub >> 6;          // 0..127
    int k32 = sub & 63;          // 0..63
    int n = n16 * 16 + (l & 15);
    int k = k32 * 32 + (l >> 4) * 8;
    const float* src = Whh + (size_t)n * H + k;
    bf16x8 o;
#pragma unroll
    for (int j = 0; j < 8; ++j) o[j] = (bf16)src[j];
    *(bf16x8*)(Wshuf + (size_t)tid * 8) = o;
}

// ---------------------------------------------------------------------------
// t = 0: S[b,i] = tanh(Whx[i]*x[b,0] + bh[i]).  One block per batch row.
// ---------------------------------------------------------------------------
__global__ void rnn_init(const float* __restrict__ x,     // [B, T]
                         const float* __restrict__ Whx,   // [H]
                         const float* __restrict__ bh,    // [H]
                         bf16* __restrict__ S) {          // [B, H]
    int b  = blockIdx.x;
    int i0 = threadIdx.x * 8;
    float xv = x[(size_t)b * TT];
    bf16x8 o;
#pragma unroll
    for (int j = 0; j < 8; ++j)
        o[j] = (bf16)tanhf(Whx[i0 + j] * xv + bh[i0 + j]);
    *(bf16x8*)(S + (size_t)b * H + i0) = o;
}

// ---------------------------------------------------------------------------
// One RNN time step:
//   Sw[b,i] = tanh( sum_k Sr[b,k]*W[i,k] + Whx[i]*x[b,t] + bh[i] )
//
// Round-9 = Round-8 with ONE change: the W operand (B) no longer goes
// through LDS. B-fragments are loaded as COALESCED 1 KB wave-segments from
// the frag-major Wshuf (see w_shuffle_kernel) straight into VGPRs, issued
// alongside the A staging and drained by the same barrier. LDS traffic per
// k-iter drops 72 -> 48 KB (A-stage 16 W + A-frag 32 R); W's 262 MB/step
// moves to the L2/L3 path, which overlaps the LDS pipe.
// (R6's B-direct failed because its unshuffled frag gathers hit 16 scattered
// 64 B segments per instruction; frag-major layout fixes exactly that.)
//
// Geometry (unchanged, best-known): 128(m) x 64(n) tile, grid 512 ->
// 2 blocks/CU co-residency (m114), single-buffered A in XOR-swizzled LDS
// (SQ_LDS_BANK_CONFLICT = 0), bm-XCD mapping (S producer-consumer L2
// locality), BK=64.
// ---------------------------------------------------------------------------
__launch_bounds__(256)
__global__ void rnn_step(const float* __restrict__ x,     // [B, T]
                         const float* __restrict__ Whx,   // [H]
                         const float* __restrict__ bh,    // [H]
                         const bf16*  __restrict__ Wshuf, // [H, H] frag-major
                         const bf16*  __restrict__ Sr,    // [B, H] read
                         bf16* __restrict__ Sw,           // [B, H] write
                         int t) {
    __shared__ __align__(16) bf16 As[128 * BK];  // 16 KB (S tile, m-rows)

    const int tid  = threadIdx.x;
    const int w    = tid >> 6;          // wave 0..3
    const int lane = tid & 63;

    // XCD-aware mapping: XCD owns batch rows (S producer-consumer locality).
    const int xcd = blockIdx.x & 7;
    const int loc = blockIdx.x >> 3;              // 0..63
    const int bm0 = (xcd * 2 + (loc & 1)) * 128;  // batch-row tile origin
    const int bn0 = (loc >> 1) * 64;              // hidden-col tile origin

    const int qm   = (w & 1) * 64;               // wave m-quadrant (64 rows)
    const int qn   = (w >> 1) * 32;              // wave n-quadrant (32 cols)
    const int lrow = lane & 15;
    const int quad = lane >> 4;

    const int s_r = tid >> 3;                    // staging row within 32-group
    const int s_l = tid & 7;                     // staging LDS chunk in row

    // B-frag source base: subtile id = n16*64 + k32; bf16 offset id*512+lane*8
    const int nb16 = (bn0 + qn) >> 4;            // n16 of fn=0 frag
    const bf16* wb = Wshuf + (size_t)lane * 8;

    f32x4 acc[4][2];
#pragma unroll
    for (int i = 0; i < 4; ++i)
#pragma unroll
        for (int j = 0; j < 2; ++j) acc[i][j] = (f32x4){0.f, 0.f, 0.f, 0.f};

    for (int k0 = 0; k0 < H; k0 += BK) {
        if (k0) __syncthreads();   // previous iter's LDS reads done
        const int kb32 = k0 >> 5;

        // B frags (VGPR, coalesced 1 KB/wave-instr), drained by the barrier
        bf16x8 bfr[2][2];          // [kc][fn]
#pragma unroll
        for (int kc = 0; kc < 2; ++kc)
#pragma unroll
            for (int fn = 0; fn < 2; ++fn)
                bfr[kc][fn] = *(const bf16x8*)(wb +
                    ((size_t)(nb16 + fn) * 64 + kb32 + kc) * 512);

        // A tile: 128 rows x 8 chunks; 4 wave-instrs (XOR-swizzled source)
#pragma unroll
        for (int i = 0; i < 4; ++i) {
            int r = i * 32 + s_r;                 // tile row 0..127
            int g = s_l ^ (r & 7);                // swizzled source chunk
            load_lds16(Sr + (size_t)(bm0 + r) * H + k0 + g * 8,
                       &As[(i * 256 + w * 64) * 8]);
        }
        __syncthreads();   // staging + B-frags complete (drains vmcnt)

#pragma unroll
        for (int kc = 0; kc < 2; ++kc) {
            bf16x8 af[4];
#pragma unroll
            for (int f = 0; f < 4; ++f) {
                int row = qm + f * 16 + lrow;
                int g   = kc * 4 + quad;
                int l   = g ^ (row & 7);
                af[f] = *(const bf16x8*)&As[(row * 8 + l) * 8];
            }
#pragma unroll
            for (int fm = 0; fm < 4; ++fm)
#pragma unroll
                for (int fn = 0; fn < 2; ++fn)
                    acc[fm][fn] = __builtin_amdgcn_mfma_f32_16x16x32_bf16(
                        af[fm], bfr[kc][fn], acc[fm][fn], 0, 0, 0);
        }
    }

    // epilogue: z += Whx[i]*x[b,t] + bh[i]; tanh; store bf16.
    // C layout (16x16x32): col = lane&15, row = quad*4 + reg  [m89-verified]
#pragma unroll
    for (int fm = 0; fm < 4; ++fm) {
        int rb = bm0 + qm + fm * 16 + quad * 4;
        float xv[4];
#pragma unroll
        for (int r = 0; r < 4; ++r) xv[r] = x[(size_t)(rb + r) * TT + t];
#pragma unroll
        for (int fn = 0; fn < 2; ++fn) {
            int col = bn0 + qn + fn * 16 + lrow;
            float wx = Whx[col], bb = bh[col];
#pragma unroll
            for (int r = 0; r < 4; ++r) {
                float z = acc[fm][fn][r] + wx * xv[r] + bb;
                Sw[(size_t)(rb + r) * H + col] = (bf16)tanhf(z);
            }
        }
    }
}

// ---------------------------------------------------------------------------
// out[b,c] = sum_h Why[h,c] * S[b,h] + bp[c]   (S = h_T^T, [B,H] bf16)
// one block per batch row
// ---------------------------------------------------------------------------
__global__ void out_proj(const bf16* __restrict__ S,
                         const float* __restrict__ Why,   // [H, C]
                         const float* __restrict__ bp,    // [C]
                         float* __restrict__ out) {       // [B, C]
    int b = blockIdx.x, tid = threadIdx.x;
    float p[NC];
#pragma unroll
    for (int c = 0; c < NC; ++c) p[c] = 0.f;
    for (int h = tid; h < H; h += 256) {
        float s = (float)S[(size_t)b * H + h];
        const float* wr = Why + h * NC;
#pragma unroll
        for (int c = 0; c < NC; ++c) p[c] += s * wr[c];
    }
    __shared__ float red[256 * NC];
#pragma unroll
    for (int c = 0; c < NC; ++c) red[tid * NC + c] = p[c];
    __syncthreads();
    for (int s = 128; s > 0; s >>= 1) {
        if (tid < s)
#pragma unroll
            for (int c = 0; c < NC; ++c) red[tid * NC + c] += red[(tid + s) * NC + c];
        __syncthreads();
    }
    if (tid < NC) out[(size_t)b * NC + tid] = red[tid] + bp[tid];
}

// ---------------------------------------------------------------------------
extern "C" void kernel_launch(void* const* d_in, const int* in_sizes, int n_in,
                              void* d_out, int out_size, void* d_ws, size_t ws_size,
                              hipStream_t stream) {
    const float* x   = (const float*)d_in[0];   // [B, T]
    const float* Whx = (const float*)d_in[1];   // [H, 1]
    const float* Whh = (const float*)d_in[2];   // [H, H]
    const float* Why = (const float*)d_in[3];   // [H, C]
    const float* bh  = (const float*)d_in[4];   // [H, 1]
    const float* bp  = (const float*)d_in[5];   // [C, 1]
    float* out = (float*)d_out;

    // workspace: Wshuf (8 MB) | S0 (8 MB) | S1 (8 MB)
    bf16* Wshuf = (bf16*)d_ws;
    bf16* S0 = (bf16*)((char*)d_ws + (size_t)8 * 1024 * 1024);
    bf16* S1 = (bf16*)((char*)d_ws + (size_t)16 * 1024 * 1024);

    hipLaunchKernelGGL(w_shuffle_kernel, dim3((H * H / 8) / 256), dim3(256),
                       0, stream, Whh, Wshuf);

    // t = 0 writes S1; step t reads (t&1 ? S1 : S0), writes the other.
    hipLaunchKernelGGL(rnn_init, dim3(BB), dim3(256), 0, stream, x, Whx, bh, S1);

    for (int t = 1; t < TT; ++t) {
        const bf16* Srd = (t & 1) ? S1 : S0;
        bf16*       Swr = (t & 1) ? S0 : S1;
        hipLaunchKernelGGL(rnn_step, dim3(512), dim3(256), 0, stream,
                           x, Whx, bh, Wshuf, Srd, Swr, t);
    }

    // t=63 (odd) wrote S0
    hipLaunchKernelGGL(out_proj, dim3(BB), dim3(256), 0, stream, S0, Why, bp, out);
}

// Round 10
// 1782.634 us; speedup vs baseline: 2.0250x; 1.0607x over previous
//
#include <hip/hip_runtime.h>
#include <cstdint>
#include <cstddef>
#include <cmath>

#define H  2048
#define BB 2048   // batch
#define TT 64     // time steps
#define NC 10     // classes
#define BK 64     // K-chunk per staging iter (8 x 16B chunks per row)

typedef __bf16 bf16;
typedef bf16  bf16x8 __attribute__((ext_vector_type(8)));
typedef bf16  bf16x4 __attribute__((ext_vector_type(4)));
typedef float f32x4  __attribute__((ext_vector_type(4)));

// ---------------------------------------------------------------------------
// async global->LDS, 16B per lane. LDS dest is wave-uniform base + lane*16.
// ---------------------------------------------------------------------------
__device__ __forceinline__ void load_lds16(const void* g, void* l) {
    __builtin_amdgcn_global_load_lds(
        (__attribute__((address_space(1))) void*)(void*)g,
        (__attribute__((address_space(3))) void*)l,
        16, 0, 0);
}

// ---------------------------------------------------------------------------
// W_hh fp32 -> bf16, shuffled into MFMA-B-frag-major layout:
// subtile (n16, k32) = 16 n-rows x 32 k, 1024 B, at id = n16*64 + k32.
// Within a subtile, dest lane-slot l (16 B) holds
//   W[n16*16 + (l&15)][k32*32 + (l>>4)*8 .. +8]
// i.e. exactly the v_mfma_f32_16x16x32_bf16 B-operand fragment, so a wave's
// B-frag load is ONE coalesced 1 KB segment: Wshuf + id*512 + lane*8 (bf16).
// ---------------------------------------------------------------------------
__global__ void w_shuffle_kernel(const float* __restrict__ Whh,
                                 bf16* __restrict__ Wshuf) {
    int tid = blockIdx.x * blockDim.x + threadIdx.x;   // 0 .. H*H/8-1
    int sub = tid >> 6;          // subtile id
    int l   = tid & 63;          // dest lane slot
    int n16 = sub >> 6;          // 0..127
    int k32 = sub & 63;          // 0..63
    int n = n16 * 16 + (l & 15);
    int k = k32 * 32 + (l >> 4) * 8;
    const float* src = Whh + (size_t)n * H + k;
    bf16x8 o;
#pragma unroll
    for (int j = 0; j < 8; ++j) o[j] = (bf16)src[j];
    *(bf16x8*)(Wshuf + (size_t)tid * 8) = o;
}

// ---------------------------------------------------------------------------
// t = 0: S[b,i] = tanh(Whx[i]*x[b,0] + bh[i]).  One block per batch row.
// ---------------------------------------------------------------------------
__global__ void rnn_init(const float* __restrict__ x,     // [B, T]
                         const float* __restrict__ Whx,   // [H]
                         const float* __restrict__ bh,    // [H]
                         bf16* __restrict__ S) {          // [B, H]
    int b  = blockIdx.x;
    int i0 = threadIdx.x * 8;
    float xv = x[(size_t)b * TT];
    bf16x8 o;
#pragma unroll
    for (int j = 0; j < 8; ++j)
        o[j] = (bf16)tanhf(Whx[i0 + j] * xv + bh[i0 + j]);
    *(bf16x8*)(S + (size_t)b * H + i0) = o;
}

// ---------------------------------------------------------------------------
// One RNN time step:
//   Sw[b,i] = tanh( sum_k Sr[b,k]*W[i,k] + Whx[i]*x[b,t] + bh[i] )
//
// Round-10 = Round-9 with the K-loop pipelined now that both prerequisites
// exist (B in coalesced VGPR frags, 2 blocks/CU co-residency):
//   - A double-buffered in LDS (2 x 16 KB), ONE barrier per k-iter (32/step,
//     was 64): prefetch of A(k+1)+B(k+1) issues right after barrier k and
//     has the whole compute(k) phase (~600 cy) in flight before barrier k+1
//     drains it. R9 serialized the raw L2/L3 load latency inside every iter.
//   - B-regs ping-pong (B0/B1) via 2x-unrolled loop: no per-iter reg copies.
//
// Geometry (unchanged): 128(m) x 64(n) tile, grid 512 -> 2 blocks/CU (m114),
// bm-XCD mapping (S producer-consumer L2 locality), XOR-swizzled A tile
// (SQ_LDS_BANK_CONFLICT = 0), frag-major Wshuf for 1 KB/wave B loads.
// LDS 32 KB/block -> 64 KB/CU at 2 blocks.
// ---------------------------------------------------------------------------
__launch_bounds__(256)
__global__ void rnn_step(const float* __restrict__ x,     // [B, T]
                         const float* __restrict__ Whx,   // [H]
                         const float* __restrict__ bh,    // [H]
                         const bf16*  __restrict__ Wshuf, // [H, H] frag-major
                         const bf16*  __restrict__ Sr,    // [B, H] read
                         bf16* __restrict__ Sw,           // [B, H] write
                         int t) {
    __shared__ __align__(16) bf16 As[2][128 * BK];  // 2 x 16 KB (S tile)

    const int tid  = threadIdx.x;
    const int w    = tid >> 6;          // wave 0..3
    const int lane = tid & 63;

    // XCD-aware mapping: XCD owns batch rows (S producer-consumer locality).
    const int xcd = blockIdx.x & 7;
    const int loc = blockIdx.x >> 3;              // 0..63
    const int bm0 = (xcd * 2 + (loc & 1)) * 128;  // batch-row tile origin
    const int bn0 = (loc >> 1) * 64;              // hidden-col tile origin

    const int qm   = (w & 1) * 64;               // wave m-quadrant (64 rows)
    const int qn   = (w >> 1) * 32;              // wave n-quadrant (32 cols)
    const int lrow = lane & 15;
    const int quad = lane >> 4;

    const int s_r = tid >> 3;                    // staging row within 32-group
    const int s_l = tid & 7;                     // staging LDS chunk in row

    // B-frag source base: subtile id = n16*64 + k32; bf16 offset id*512+lane*8
    const int nb16 = (bn0 + qn) >> 4;            // n16 of fn=0 frag
    const bf16* wb = Wshuf + (size_t)lane * 8;

    auto stageA = [&](int b, int k0) {
#pragma unroll
        for (int i = 0; i < 4; ++i) {
            int r = i * 32 + s_r;                 // tile row 0..127
            int g = s_l ^ (r & 7);                // swizzled source chunk
            load_lds16(Sr + (size_t)(bm0 + r) * H + k0 + g * 8,
                       &As[b][(i * 256 + w * 64) * 8]);
        }
    };
    auto loadB = [&](bf16x8 (&B)[2][2], int k0) {
        const int kb32 = k0 >> 5;
#pragma unroll
        for (int kc = 0; kc < 2; ++kc)
#pragma unroll
            for (int fn = 0; fn < 2; ++fn)
                B[kc][fn] = *(const bf16x8*)(wb +
                    ((size_t)(nb16 + fn) * 64 + kb32 + kc) * 512);
    };

    f32x4 acc[4][2];
#pragma unroll
    for (int i = 0; i < 4; ++i)
#pragma unroll
        for (int j = 0; j < 2; ++j) acc[i][j] = (f32x4){0.f, 0.f, 0.f, 0.f};

    auto compute = [&](const bf16* Ab, bf16x8 (&B)[2][2]) {
#pragma unroll
        for (int kc = 0; kc < 2; ++kc) {
            bf16x8 af[4];
#pragma unroll
            for (int f = 0; f < 4; ++f) {
                int row = qm + f * 16 + lrow;
                int g   = kc * 4 + quad;
                int l   = g ^ (row & 7);
                af[f] = *(const bf16x8*)&Ab[(row * 8 + l) * 8];
            }
#pragma unroll
            for (int fm = 0; fm < 4; ++fm)
#pragma unroll
                for (int fn = 0; fn < 2; ++fn)
                    acc[fm][fn] = __builtin_amdgcn_mfma_f32_16x16x32_bf16(
                        af[fm], B[kc][fn], acc[fm][fn], 0, 0, 0);
        }
    };

    bf16x8 B0[2][2], B1[2][2];
    stageA(0, 0);
    loadB(B0, 0);

    for (int k0 = 0; k0 < H; k0 += 2 * BK) {
        __syncthreads();                          // drains A(k0) stage + B0
        if (k0 + BK < H) { loadB(B1, k0 + BK); stageA(1, k0 + BK); }
        compute(As[0], B0);

        __syncthreads();                          // drains A(k0+BK) + B1
        if (k0 + 2 * BK < H) { loadB(B0, k0 + 2 * BK); stageA(0, k0 + 2 * BK); }
        compute(As[1], B1);
    }

    // epilogue: z += Whx[i]*x[b,t] + bh[i]; tanh; store bf16.
    // C layout (16x16x32): col = lane&15, row = quad*4 + reg  [m89-verified]
#pragma unroll
    for (int fm = 0; fm < 4; ++fm) {
        int rb = bm0 + qm + fm * 16 + quad * 4;
        float xv[4];
#pragma unroll
        for (int r = 0; r < 4; ++r) xv[r] = x[(size_t)(rb + r) * TT + t];
#pragma unroll
        for (int fn = 0; fn < 2; ++fn) {
            int col = bn0 + qn + fn * 16 + lrow;
            float wx = Whx[col], bb = bh[col];
#pragma unroll
            for (int r = 0; r < 4; ++r) {
                float z = acc[fm][fn][r] + wx * xv[r] + bb;
                Sw[(size_t)(rb + r) * H + col] = (bf16)tanhf(z);
            }
        }
    }
}

// ---------------------------------------------------------------------------
// out[b,c] = sum_h Why[h,c] * S[b,h] + bp[c]   (S = h_T^T, [B,H] bf16)
// one block per batch row
// ---------------------------------------------------------------------------
__global__ void out_proj(const bf16* __restrict__ S,
                         const float* __restrict__ Why,   // [H, C]
                         const float* __restrict__ bp,    // [C]
                         float* __restrict__ out) {       // [B, C]
    int b = blockIdx.x, tid = threadIdx.x;
    float p[NC];
#pragma unroll
    for (int c = 0; c < NC; ++c) p[c] = 0.f;
    for (int h = tid; h < H; h += 256) {
        float s = (float)S[(size_t)b * H + h];
        const float* wr = Why + h * NC;
#pragma unroll
        for (int c = 0; c < NC; ++c) p[c] += s * wr[c];
    }
    __shared__ float red[256 * NC];
#pragma unroll
    for (int c = 0; c < NC; ++c) red[tid * NC + c] = p[c];
    __syncthreads();
    for (int s = 128; s > 0; s >>= 1) {
        if (tid < s)
#pragma unroll
            for (int c = 0; c < NC; ++c) red[tid * NC + c] += red[(tid + s) * NC + c];
        __syncthreads();
    }
    if (tid < NC) out[(size_t)b * NC + tid] = red[tid] + bp[tid];
}

// ---------------------------------------------------------------------------
extern "C" void kernel_launch(void* const* d_in, const int* in_sizes, int n_in,
                              void* d_out, int out_size, void* d_ws, size_t ws_size,
                              hipStream_t stream) {
    const float* x   = (const float*)d_in[0];   // [B, T]
    const float* Whx = (const float*)d_in[1];   // [H, 1]
    const float* Whh = (const float*)d_in[2];   // [H, H]
    const float* Why = (const float*)d_in[3];   // [H, C]
    const float* bh  = (const float*)d_in[4];   // [H, 1]
    const float* bp  = (const float*)d_in[5];   // [C, 1]
    float* out = (float*)d_out;

    // workspace: Wshuf (8 MB) | S0 (8 MB) | S1 (8 MB)
    bf16* Wshuf = (bf16*)d_ws;
    bf16* S0 = (bf16*)((char*)d_ws + (size_t)8 * 1024 * 1024);
    bf16* S1 = (bf16*)((char*)d_ws + (size_t)16 * 1024 * 1024);

    hipLaunchKernelGGL(w_shuffle_kernel, dim3((H * H / 8) / 256), dim3(256),
                       0, stream, Whh, Wshuf);

    // t = 0 writes S1; step t reads (t&1 ? S1 : S0), writes the other.
    hipLaunchKernelGGL(rnn_init, dim3(BB), dim3(256), 0, stream, x, Whx, bh, S1);

    for (int t = 1; t < TT; ++t) {
        const bf16* Srd = (t & 1) ? S1 : S0;
        bf16*       Swr = (t & 1) ? S0 : S1;
        hipLaunchKernelGGL(rnn_step, dim3(512), dim3(256), 0, stream,
                           x, Whx, bh, Wshuf, Srd, Swr, t);
    }

    // t=63 (odd) wrote S0
    hipLaunchKernelGGL(out_proj, dim3(BB), dim3(256), 0, stream, S0, Why, bp, out);
}